// Round 1
// baseline (73.333 us; speedup 1.0000x reference)
//
#include <hip/hip_runtime.h>
#include <math.h>

#define NB 4096
#define NC 512
#define NF 128
#define TAUc 32.0f
#define ALPHAc 0.9f

// ---------------- prep: normalize means, inv = exp(-clip(lv)), store f-major ----
__global__ __launch_bounds__(128) void k_prep(const float* __restrict__ means,
                                              const float* __restrict__ logv,
                                              float* __restrict__ mu_t,
                                              float* __restrict__ iv_t) {
  int c = blockIdx.x, f = threadIdx.x;
  float mu = means[c * NF + f];
  float lv = logv[c * NF + f];
  lv = fminf(fmaxf(lv, 0.0f), 6.0f);
  float iv = __expf(-lv);
  float s = mu * mu;
  #pragma unroll
  for (int o = 1; o < 64; o <<= 1) s += __shfl_xor(s, o, 64);
  __shared__ float part[2];
  if ((threadIdx.x & 63) == 0) part[threadIdx.x >> 6] = s;
  __syncthreads();
  float tot = part[0] + part[1];
  float mun = mu / fmaxf(sqrtf(tot), 1e-12f);
  mu_t[f * NC + c] = mun;   // f-major for coalesced LDS staging later
  iv_t[f * NC + c] = iv;
}

// ---------------- column mask: colnz[c] = any(T[:,c]) ----------------------------
__global__ __launch_bounds__(256) void k_mask(const int* __restrict__ T,
                                              int* __restrict__ colnz) {
  int r0 = blockIdx.x * 16;
  int a0 = 0, a1 = 0;
  for (int r = 0; r < 16; ++r) {
    const int* row = T + (size_t)(r0 + r) * NC;
    a0 |= row[threadIdx.x];
    a1 |= row[threadIdx.x + 256];
  }
  if (a0) atomicOr(colnz + threadIdx.x, 1);
  if (a1) atomicOr(colnz + threadIdx.x + 256, 1);
}

// ---------------- exclusive prefix scan of mask -> output column positions -------
__global__ __launch_bounds__(512) void k_scan(const int* __restrict__ colnz,
                                              int* __restrict__ pos) {
  __shared__ int s[NC];
  int t = threadIdx.x;
  int f = colnz[t] ? 1 : 0;
  s[t] = f;
  __syncthreads();
  for (int o = 1; o < NC; o <<= 1) {
    int add = (t >= o) ? s[t - o] : 0;
    __syncthreads();
    s[t] += add;
    __syncthreads();
  }
  pos[t] = s[t] - f;
}

// ---------------- main: D + softmax + S + per-row loss terms ---------------------
// 16 rows/block, 256 threads (4 waves). ty=tid/64 owns rows ty*4..ty*4+3 (TM=4),
// tx=tid%63 owns cols tx+64j, j=0..7 (TN=8).
__global__ __launch_bounds__(256) void k_main(const float* __restrict__ X,
                                              const int* __restrict__ T,
                                              const float* __restrict__ mu_t,
                                              const float* __restrict__ iv_t,
                                              const int* __restrict__ colnz,
                                              const int* __restrict__ pos,
                                              float* __restrict__ rowlog,
                                              int* __restrict__ rowcnt,
                                              float* __restrict__ out,
                                              int Csel) {
  __shared__ float Xs[16 * NF];     // 8 KB
  __shared__ float Mus[16 * NC];    // 32 KB chunk of mu (f-major)
  __shared__ float Ivs[16 * NC];    // 32 KB chunk of inv
  __shared__ float rsc[16];
  int tid = threadIdx.x;
  int r0 = blockIdx.x * 16;

  // stage X rows (coalesced float4)
  const float4* Xg = (const float4*)(X + (size_t)r0 * NF);
  for (int k = tid; k < 16 * NF / 4; k += 256) ((float4*)Xs)[k] = Xg[k];
  __syncthreads();
  // row norms: 16 threads per row
  {
    int row = tid >> 4, l16 = tid & 15;
    float s = 0.f;
    #pragma unroll
    for (int q = 0; q < 8; ++q) { float x = Xs[row * NF + l16 * 8 + q]; s = fmaf(x, x, s); }
    #pragma unroll
    for (int o = 1; o < 16; o <<= 1) s += __shfl_xor(s, o, 64);
    if (l16 == 0) rsc[row] = 1.0f / fmaxf(sqrtf(s), 1e-12f);
  }
  __syncthreads();
  for (int k = tid; k < 16 * NF; k += 256) Xs[k] *= rsc[k >> 7];
  __syncthreads();

  int ty = tid >> 6, tx = tid & 63;
  float acc[4][8];
  #pragma unroll
  for (int i = 0; i < 4; ++i)
    #pragma unroll
    for (int j = 0; j < 8; ++j) acc[i][j] = 0.f;

  for (int f0 = 0; f0 < NF; f0 += 16) {
    const float4* mg = (const float4*)(mu_t + (size_t)f0 * NC);
    const float4* ig = (const float4*)(iv_t + (size_t)f0 * NC);
    for (int k = tid; k < 16 * NC / 4; k += 256) {
      ((float4*)Mus)[k] = mg[k];
      ((float4*)Ivs)[k] = ig[k];
    }
    __syncthreads();
    #pragma unroll
    for (int fl = 0; fl < 16; ++fl) {
      float xv[4];
      #pragma unroll
      for (int i = 0; i < 4; ++i) xv[i] = Xs[(ty * 4 + i) * NF + f0 + fl];  // LDS broadcast
      #pragma unroll
      for (int j = 0; j < 8; ++j) {
        float m = Mus[fl * NC + tx + 64 * j];   // bank = tx%32 -> 2-way, free
        float v = Ivs[fl * NC + tx + 64 * j];
        #pragma unroll
        for (int i = 0; i < 4; ++i) {
          float d = xv[i] - m;
          acc[i][j] = fmaf(d * d, v, acc[i][j]);
        }
      }
    }
    __syncthreads();
  }

  // per-column metadata (same cols for all my rows)
  int cn[8], pp[8];
  #pragma unroll
  for (int j = 0; j < 8; ++j) { int c = tx + 64 * j; cn[j] = colnz[c]; pp[j] = pos[c]; }

  #pragma unroll
  for (int i = 0; i < 4; ++i) {
    int r = r0 + ty * 4 + i;
    float dmin = acc[i][0];
    #pragma unroll
    for (int j = 1; j < 8; ++j) dmin = fminf(dmin, acc[i][j]);
    #pragma unroll
    for (int o = 1; o < 64; o <<= 1) dmin = fminf(dmin, __shfl_xor(dmin, o, 64));
    const int* Trow = T + (size_t)r * NC;
    int tf[8];
    #pragma unroll
    for (int j = 0; j < 8; ++j) tf[j] = Trow[tx + 64 * j];
    float Z = 0.f, Ps = 0.f;
    #pragma unroll
    for (int j = 0; j < 8; ++j) {
      float p = __expf(TAUc * (dmin - acc[i][j]));
      Z += p;
      if (tf[j]) Ps += p;
    }
    #pragma unroll
    for (int o = 1; o < 64; o <<= 1) { Z += __shfl_xor(Z, o, 64); Ps += __shfl_xor(Ps, o, 64); }
    // S row (coalesced per j)
    float* orow = out + 1 + (size_t)r * Csel;
    #pragma unroll
    for (int j = 0; j < 8; ++j) {
      if (cn[j]) orow[pp[j]] = tf[j] ? 1.0f : __expf(-ALPHAc * acc[i][j]);
    }
    if (tx == 0) {
      float Psum = Ps / Z;
      rowlog[r] = (Psum > 0.f) ? logf(Psum) : 0.f;
      rowcnt[r] = (Psum > 0.f) ? 1 : 0;
    }
  }
}

// ---------------- finalize loss (deterministic fixed-order reduction) ------------
__global__ __launch_bounds__(256) void k_fin(const float* __restrict__ rowlog,
                                             const int* __restrict__ rowcnt,
                                             float* __restrict__ out) {
  __shared__ float sl[256];
  __shared__ int sc[256];
  int t = threadIdx.x;
  float s = 0.f; int c = 0;
  for (int r = t; r < NB; r += 256) { s += rowlog[r]; c += rowcnt[r]; }
  sl[t] = s; sc[t] = c;
  __syncthreads();
  for (int o = 128; o > 0; o >>= 1) {
    if (t < o) { sl[t] += sl[t + o]; sc[t] += sc[t + o]; }
    __syncthreads();
  }
  if (t == 0) out[0] = -sl[0] / fmaxf((float)sc[0], 1.0f);
}

extern "C" void kernel_launch(void* const* d_in, const int* in_sizes, int n_in,
                              void* d_out, int out_size, void* d_ws, size_t ws_size,
                              hipStream_t stream) {
  const float* X     = (const float*)d_in[0];
  const int*   T     = (const int*)d_in[1];
  const float* means = (const float*)d_in[2];
  const float* logv  = (const float*)d_in[3];
  float* out = (float*)d_out;
  char* ws = (char*)d_ws;
  float* mu_t   = (float*)(ws);                 // 256 KB
  float* iv_t   = (float*)(ws + 256 * 1024);    // 256 KB
  float* rowlog = (float*)(ws + 512 * 1024);    // 16 KB
  int*   rowcnt = (int*)  (ws + 528 * 1024);    // 16 KB
  int*   colnz  = (int*)  (ws + 544 * 1024);    // 2 KB
  int*   pos    = (int*)  (ws + 546 * 1024);    // 2 KB

  int Csel = (out_size - 1) / NB;               // = number of selected columns

  hipMemsetAsync(colnz, 0, NC * sizeof(int), stream);
  k_prep<<<NC, NF, 0, stream>>>(means, logv, mu_t, iv_t);
  k_mask<<<NB / 16, 256, 0, stream>>>(T, colnz);
  k_scan<<<1, NC, 0, stream>>>(colnz, pos);
  k_main<<<NB / 16, 256, 0, stream>>>(X, T, mu_t, iv_t, colnz, pos, rowlog, rowcnt, out, Csel);
  k_fin<<<1, 256, 0, stream>>>(rowlog, rowcnt, out);
}

// Round 2
// 66.028 us; speedup vs baseline: 1.1106x; 1.1106x over previous
//
#include <hip/hip_runtime.h>
#include <hip/hip_bf16.h>
#include <math.h>

#define NB 4096
#define NC 512
#define NF 128
#define NK 256           // base GEMM K = 2*F
#define TAUc 32.0f
#define ALPHAc 0.9f

typedef __attribute__((ext_vector_type(8))) short bf16x8;
typedef __attribute__((ext_vector_type(4))) float f32x4;

__device__ inline ushort f2bf(float x) {
  __hip_bfloat16 h = __float2bfloat16(x);
  return *reinterpret_cast<ushort*>(&h);
}
__device__ inline float bf2f(ushort u) {
  __hip_bfloat16 h = *reinterpret_cast<__hip_bfloat16*>(&u);
  return __bfloat162float(h);
}

// ---------- prepA: Xn = l2norm(X); A = [Xn^2, Xn] split into bf16 hi/lo ----------
__global__ __launch_bounds__(128) void k_prepA(const float* __restrict__ X,
                                               ushort* __restrict__ Ah,
                                               ushort* __restrict__ Al) {
  int b = blockIdx.x, f = threadIdx.x;
  float x = X[(size_t)b * NF + f];
  float s = x * x;
  #pragma unroll
  for (int o = 1; o < 64; o <<= 1) s += __shfl_xor(s, o, 64);
  __shared__ float p2[2];
  if ((f & 63) == 0) p2[f >> 6] = s;
  __syncthreads();
  float xn = x / fmaxf(sqrtf(p2[0] + p2[1]), 1e-12f);
  float a1 = xn * xn;
  ushort h1 = f2bf(a1);
  Ah[(size_t)b * NK + f] = h1;
  Al[(size_t)b * NK + f] = f2bf(a1 - bf2f(h1));
  ushort h2 = f2bf(xn);
  Ah[(size_t)b * NK + NF + f] = h2;
  Al[(size_t)b * NK + NF + f] = f2bf(xn - bf2f(h2));
}

// ---------- prepB: mu_n, iv=exp(-clip(lv)); Bt = [iv, -2*mu_n*iv] hi/lo; t3 -------
__global__ __launch_bounds__(128) void k_prepB(const float* __restrict__ means,
                                               const float* __restrict__ logv,
                                               ushort* __restrict__ Bh,
                                               ushort* __restrict__ Bl,
                                               float* __restrict__ t3) {
  int c = blockIdx.x, f = threadIdx.x;
  float mu = means[(size_t)c * NF + f];
  float lv = fminf(fmaxf(logv[(size_t)c * NF + f], 0.f), 6.f);
  float iv = __expf(-lv);
  float s = mu * mu;
  #pragma unroll
  for (int o = 1; o < 64; o <<= 1) s += __shfl_xor(s, o, 64);
  __shared__ float p2[2];
  __shared__ float q2[2];
  if ((f & 63) == 0) p2[f >> 6] = s;
  __syncthreads();
  float mun = mu / fmaxf(sqrtf(p2[0] + p2[1]), 1e-12f);
  float b1 = iv;
  float b2 = -2.f * mun * iv;
  ushort h1 = f2bf(b1);
  Bh[(size_t)c * NK + f] = h1;
  Bl[(size_t)c * NK + f] = f2bf(b1 - bf2f(h1));
  ushort h2 = f2bf(b2);
  Bh[(size_t)c * NK + NF + f] = h2;
  Bl[(size_t)c * NK + NF + f] = f2bf(b2 - bf2f(h2));
  // t3[c] = sum mun^2 * iv
  float t = mun * mun * iv;
  #pragma unroll
  for (int o = 1; o < 64; o <<= 1) t += __shfl_xor(t, o, 64);
  if ((f & 63) == 0) q2[f >> 6] = t;
  __syncthreads();
  if (f == 0) t3[c] = q2[0] + q2[1];
}

// ---------- column mask + scan (unchanged, cheap) --------------------------------
__global__ __launch_bounds__(256) void k_mask(const int* __restrict__ T,
                                              int* __restrict__ colnz) {
  int r0 = blockIdx.x * 16;
  int a0 = 0, a1 = 0;
  for (int r = 0; r < 16; ++r) {
    const int* row = T + (size_t)(r0 + r) * NC;
    a0 |= row[threadIdx.x];
    a1 |= row[threadIdx.x + 256];
  }
  if (a0) atomicOr(colnz + threadIdx.x, 1);
  if (a1) atomicOr(colnz + threadIdx.x + 256, 1);
}

__global__ __launch_bounds__(512) void k_scan(const int* __restrict__ colnz,
                                              int* __restrict__ pos) {
  __shared__ int s[NC];
  int t = threadIdx.x;
  int f = colnz[t] ? 1 : 0;
  s[t] = f;
  __syncthreads();
  for (int o = 1; o < NC; o <<= 1) {
    int add = (t >= o) ? s[t - o] : 0;
    __syncthreads();
    s[t] += add;
    __syncthreads();
  }
  pos[t] = s[t] - f;
}

// ---------- GEMM: D = Ah*Bh + Al*Bh + Ah*Bl + t3  (MFMA, operands from L2) -------
// 64x64 block tile, 4 waves in 2x2, each wave 2x2 of 16x16x32 MFMA tiles.
__global__ __launch_bounds__(256) void k_gemm(const ushort* __restrict__ Ah,
                                              const ushort* __restrict__ Al,
                                              const ushort* __restrict__ Bh,
                                              const ushort* __restrict__ Bl,
                                              const float* __restrict__ t3,
                                              float* __restrict__ D) {
  int tid = threadIdx.x;
  int lane = tid & 63, wave = tid >> 6;
  int wm = wave & 1, wn = wave >> 1;
  int m0 = blockIdx.x * 64 + wm * 32;
  int n0 = blockIdx.y * 64 + wn * 32;
  int lr = lane & 15;        // row (A) / col (B) within 16-tile
  int kq = lane >> 4;        // k-quarter: k = 8*kq + j
  int koffl = 8 * kq;

  f32x4 acc[2][2] = {};
  #pragma unroll
  for (int seg = 0; seg < 3; ++seg) {
    const ushort* ap = (seg == 1) ? Al : Ah;
    const ushort* bp = (seg == 2) ? Bl : Bh;
    const ushort* a0p = ap + (size_t)(m0 + lr) * NK + koffl;
    const ushort* a1p = ap + (size_t)(m0 + 16 + lr) * NK + koffl;
    const ushort* b0p = bp + (size_t)(n0 + lr) * NK + koffl;
    const ushort* b1p = bp + (size_t)(n0 + 16 + lr) * NK + koffl;
    #pragma unroll 4
    for (int k8 = 0; k8 < 8; ++k8) {
      int kb = k8 * 32;
      bf16x8 a0 = *(const bf16x8*)(a0p + kb);
      bf16x8 a1 = *(const bf16x8*)(a1p + kb);
      bf16x8 b0 = *(const bf16x8*)(b0p + kb);
      bf16x8 b1 = *(const bf16x8*)(b1p + kb);
      acc[0][0] = __builtin_amdgcn_mfma_f32_16x16x32_bf16(a0, b0, acc[0][0], 0, 0, 0);
      acc[1][0] = __builtin_amdgcn_mfma_f32_16x16x32_bf16(a1, b0, acc[1][0], 0, 0, 0);
      acc[0][1] = __builtin_amdgcn_mfma_f32_16x16x32_bf16(a0, b1, acc[0][1], 0, 0, 0);
      acc[1][1] = __builtin_amdgcn_mfma_f32_16x16x32_bf16(a1, b1, acc[1][1], 0, 0, 0);
    }
  }
  // epilogue: D[r][c] = acc + t3[c]   (C/D layout: col=lane&15, row=4*(lane>>4)+i)
  int rbase = 4 * kq;
  #pragma unroll
  for (int rt = 0; rt < 2; ++rt) {
    #pragma unroll
    for (int ct = 0; ct < 2; ++ct) {
      int c = n0 + 16 * ct + lr;
      float tt = t3[c];
      #pragma unroll
      for (int i = 0; i < 4; ++i) {
        int r = m0 + 16 * rt + rbase + i;
        D[(size_t)r * NC + c] = acc[rt][ct][i] + tt;
      }
    }
  }
}

// ---------- epilogue: softmax over C, S, per-row loss terms ----------------------
// 4 waves/block, 1 row per wave; lane owns cols lane+64j.
__global__ __launch_bounds__(256) void k_epi(const int* __restrict__ T,
                                             const int* __restrict__ colnz,
                                             const int* __restrict__ pos,
                                             const float* __restrict__ Din,
                                             float* __restrict__ Sout,
                                             float* __restrict__ rowlog,
                                             int* __restrict__ rowcnt,
                                             int Csel) {
  int lane = threadIdx.x & 63, w = threadIdx.x >> 6;
  int r = blockIdx.x * 4 + w;
  const float* drow = Din + (size_t)r * NC;
  const int* Trow = T + (size_t)r * NC;
  float d[8]; int tf[8];
  #pragma unroll
  for (int j = 0; j < 8; ++j) {
    d[j] = drow[lane + 64 * j];
    tf[j] = Trow[lane + 64 * j];
  }
  float dmin = d[0];
  #pragma unroll
  for (int j = 1; j < 8; ++j) dmin = fminf(dmin, d[j]);
  #pragma unroll
  for (int o = 1; o < 64; o <<= 1) dmin = fminf(dmin, __shfl_xor(dmin, o, 64));
  float Z = 0.f, Ps = 0.f;
  #pragma unroll
  for (int j = 0; j < 8; ++j) {
    float p = __expf(TAUc * (dmin - d[j]));
    Z += p;
    if (tf[j]) Ps += p;
  }
  #pragma unroll
  for (int o = 1; o < 64; o <<= 1) { Z += __shfl_xor(Z, o, 64); Ps += __shfl_xor(Ps, o, 64); }
  float sv[8]; int cn[8], pp[8];
  #pragma unroll
  for (int j = 0; j < 8; ++j) {
    sv[j] = tf[j] ? 1.0f : __expf(-ALPHAc * d[j]);
    int c = lane + 64 * j;
    cn[j] = colnz[c];
    pp[j] = pos[c];
  }
  __syncthreads();   // all reads of this block's D rows done before in-place writes
  float* srow = Sout + (size_t)r * Csel;
  #pragma unroll
  for (int j = 0; j < 8; ++j) if (cn[j]) srow[pp[j]] = sv[j];
  if (lane == 0) {
    float Psum = Ps / Z;
    rowlog[r] = (Psum > 0.f) ? logf(Psum) : 0.f;
    rowcnt[r] = (Psum > 0.f) ? 1 : 0;
  }
}

// ---------- finalize loss --------------------------------------------------------
__global__ __launch_bounds__(256) void k_fin(const float* __restrict__ rowlog,
                                             const int* __restrict__ rowcnt,
                                             float* __restrict__ out) {
  __shared__ float sl[256];
  __shared__ int sc[256];
  int t = threadIdx.x;
  float s = 0.f; int c = 0;
  for (int r = t; r < NB; r += 256) { s += rowlog[r]; c += rowcnt[r]; }
  sl[t] = s; sc[t] = c;
  __syncthreads();
  for (int o = 128; o > 0; o >>= 1) {
    if (t < o) { sl[t] += sl[t + o]; sc[t] += sc[t + o]; }
    __syncthreads();
  }
  if (t == 0) out[0] = -sl[0] / fmaxf((float)sc[0], 1.0f);
}

extern "C" void kernel_launch(void* const* d_in, const int* in_sizes, int n_in,
                              void* d_out, int out_size, void* d_ws, size_t ws_size,
                              hipStream_t stream) {
  const float* X     = (const float*)d_in[0];
  const int*   T     = (const int*)d_in[1];
  const float* means = (const float*)d_in[2];
  const float* logv  = (const float*)d_in[3];
  float* out = (float*)d_out;
  char* ws = (char*)d_ws;

  ushort* Ah    = (ushort*)(ws);                       // 2 MB
  ushort* Al    = (ushort*)(ws + 2097152);             // 2 MB
  ushort* Bh    = (ushort*)(ws + 4194304);             // 256 KB
  ushort* Bl    = (ushort*)(ws + 4456448);             // 256 KB
  float*  t3    = (float*) (ws + 4718592);             // 2 KB
  float*  rowlog= (float*) (ws + 4720640);             // 16 KB
  int*    rowcnt= (int*)   (ws + 4737024);             // 16 KB
  int*    colnz = (int*)   (ws + 4753408);             // 2 KB
  int*    pos   = (int*)   (ws + 4755456);             // 2 KB
  float*  Dfb   = (float*) (ws + 4757504);             // 8 MB fallback (Csel<512 only)

  int Csel = (out_size - 1) / NB;
  // D lives in-place in d_out when all columns are selected (the practical case).
  float* Din = (Csel == NC) ? (out + 1) : Dfb;

  hipMemsetAsync(colnz, 0, NC * sizeof(int), stream);
  k_prepA<<<NB, NF, 0, stream>>>(X, Ah, Al);
  k_prepB<<<NC, NF, 0, stream>>>(means, logv, Bh, Bl, t3);
  k_mask<<<NB / 16, 256, 0, stream>>>(T, colnz);
  k_scan<<<1, NC, 0, stream>>>(colnz, pos);
  k_gemm<<<dim3(NB / 64, NC / 64), 256, 0, stream>>>(Ah, Al, Bh, Bl, t3, Din);
  k_epi<<<NB / 4, 256, 0, stream>>>(T, colnz, pos, Din, out + 1, rowlog, rowcnt, Csel);
  k_fin<<<1, 256, 0, stream>>>(rowlog, rowcnt, out);
}

// Round 3
// 45.012 us; speedup vs baseline: 1.6292x; 1.4669x over previous
//
#include <hip/hip_runtime.h>
#include <hip/hip_bf16.h>
#include <math.h>

#define NB 4096
#define NC 512
#define NF 128
#define NK 256           // base GEMM K = 2*F
#define TAUc 32.0f
#define ALPHAc 0.9f

typedef __attribute__((ext_vector_type(8))) short bf16x8;
typedef __attribute__((ext_vector_type(4))) float f32x4;

__device__ inline ushort f2bf(float x) {
  __hip_bfloat16 h = __float2bfloat16(x);
  return *reinterpret_cast<ushort*>(&h);
}
__device__ inline float bf2f(ushort u) {
  __hip_bfloat16 h = *reinterpret_cast<__hip_bfloat16*>(&u);
  return __bfloat162float(h);
}

// ---------- prep (combined): blocks [0,NB) do X->A, blocks [NB,NB+NC) do means->B
__global__ __launch_bounds__(128) void k_prep(const float* __restrict__ X,
                                              const float* __restrict__ means,
                                              const float* __restrict__ logv,
                                              ushort* __restrict__ Ah,
                                              ushort* __restrict__ Al,
                                              ushort* __restrict__ Bh,
                                              ushort* __restrict__ Bl,
                                              float* __restrict__ t3) {
  __shared__ float p2[2];
  __shared__ float q2[2];
  int f = threadIdx.x;
  if (blockIdx.x < NB) {
    int b = blockIdx.x;
    float x = X[(size_t)b * NF + f];
    float s = x * x;
    #pragma unroll
    for (int o = 1; o < 64; o <<= 1) s += __shfl_xor(s, o, 64);
    if ((f & 63) == 0) p2[f >> 6] = s;
    __syncthreads();
    float xn = x / fmaxf(sqrtf(p2[0] + p2[1]), 1e-12f);
    float a1 = xn * xn;
    ushort h1 = f2bf(a1);
    Ah[(size_t)b * NK + f] = h1;
    Al[(size_t)b * NK + f] = f2bf(a1 - bf2f(h1));
    ushort h2 = f2bf(xn);
    Ah[(size_t)b * NK + NF + f] = h2;
    Al[(size_t)b * NK + NF + f] = f2bf(xn - bf2f(h2));
  } else {
    int c = blockIdx.x - NB;
    float mu = means[(size_t)c * NF + f];
    float lv = fminf(fmaxf(logv[(size_t)c * NF + f], 0.f), 6.f);
    float iv = __expf(-lv);
    float s = mu * mu;
    #pragma unroll
    for (int o = 1; o < 64; o <<= 1) s += __shfl_xor(s, o, 64);
    if ((f & 63) == 0) p2[f >> 6] = s;
    __syncthreads();
    float mun = mu / fmaxf(sqrtf(p2[0] + p2[1]), 1e-12f);
    float b1 = iv;
    float b2 = -2.f * mun * iv;
    ushort h1 = f2bf(b1);
    Bh[(size_t)c * NK + f] = h1;
    Bl[(size_t)c * NK + f] = f2bf(b1 - bf2f(h1));
    ushort h2 = f2bf(b2);
    Bh[(size_t)c * NK + NF + f] = h2;
    Bl[(size_t)c * NK + NF + f] = f2bf(b2 - bf2f(h2));
    float t = mun * mun * iv;
    #pragma unroll
    for (int o = 1; o < 64; o <<= 1) t += __shfl_xor(t, o, 64);
    if ((f & 63) == 0) q2[f >> 6] = t;
    __syncthreads();
    if (f == 0) t3[c] = q2[0] + q2[1];
  }
}

// ---------- fallback-only: zero mask, build mask, scan (not launched when Csel==NC)
__global__ __launch_bounds__(512) void k_zero(int* __restrict__ colnz) {
  colnz[threadIdx.x] = 0;
}

__global__ __launch_bounds__(256) void k_mask(const int* __restrict__ T,
                                              int* __restrict__ colnz) {
  int r0 = blockIdx.x * 16;
  int a0 = 0, a1 = 0;
  for (int r = 0; r < 16; ++r) {
    const int* row = T + (size_t)(r0 + r) * NC;
    a0 |= row[threadIdx.x];
    a1 |= row[threadIdx.x + 256];
  }
  if (a0) atomicOr(colnz + threadIdx.x, 1);
  if (a1) atomicOr(colnz + threadIdx.x + 256, 1);
}

__global__ __launch_bounds__(512) void k_scan(const int* __restrict__ colnz,
                                              int* __restrict__ pos) {
  __shared__ int s[NC];
  int t = threadIdx.x;
  int f = colnz[t] ? 1 : 0;
  s[t] = f;
  __syncthreads();
  for (int o = 1; o < NC; o <<= 1) {
    int add = (t >= o) ? s[t - o] : 0;
    __syncthreads();
    s[t] += add;
    __syncthreads();
  }
  pos[t] = s[t] - f;
}

// ---------- GEMM: D = Ah*Bh + Al*Bh + Ah*Bl + t3  (MFMA, operands from L2) -------
__global__ __launch_bounds__(256) void k_gemm(const ushort* __restrict__ Ah,
                                              const ushort* __restrict__ Al,
                                              const ushort* __restrict__ Bh,
                                              const ushort* __restrict__ Bl,
                                              const float* __restrict__ t3,
                                              float* __restrict__ D) {
  int tid = threadIdx.x;
  int lane = tid & 63, wave = tid >> 6;
  int wm = wave & 1, wn = wave >> 1;
  int m0 = blockIdx.x * 64 + wm * 32;
  int n0 = blockIdx.y * 64 + wn * 32;
  int lr = lane & 15;
  int kq = lane >> 4;
  int koffl = 8 * kq;

  f32x4 acc[2][2] = {};
  #pragma unroll
  for (int seg = 0; seg < 3; ++seg) {
    const ushort* ap = (seg == 1) ? Al : Ah;
    const ushort* bp = (seg == 2) ? Bl : Bh;
    const ushort* a0p = ap + (size_t)(m0 + lr) * NK + koffl;
    const ushort* a1p = ap + (size_t)(m0 + 16 + lr) * NK + koffl;
    const ushort* b0p = bp + (size_t)(n0 + lr) * NK + koffl;
    const ushort* b1p = bp + (size_t)(n0 + 16 + lr) * NK + koffl;
    #pragma unroll 4
    for (int k8 = 0; k8 < 8; ++k8) {
      int kb = k8 * 32;
      bf16x8 a0 = *(const bf16x8*)(a0p + kb);
      bf16x8 a1 = *(const bf16x8*)(a1p + kb);
      bf16x8 b0 = *(const bf16x8*)(b0p + kb);
      bf16x8 b1 = *(const bf16x8*)(b1p + kb);
      acc[0][0] = __builtin_amdgcn_mfma_f32_16x16x32_bf16(a0, b0, acc[0][0], 0, 0, 0);
      acc[1][0] = __builtin_amdgcn_mfma_f32_16x16x32_bf16(a1, b0, acc[1][0], 0, 0, 0);
      acc[0][1] = __builtin_amdgcn_mfma_f32_16x16x32_bf16(a0, b1, acc[0][1], 0, 0, 0);
      acc[1][1] = __builtin_amdgcn_mfma_f32_16x16x32_bf16(a1, b1, acc[1][1], 0, 0, 0);
    }
  }
  int rbase = 4 * kq;
  #pragma unroll
  for (int rt = 0; rt < 2; ++rt) {
    #pragma unroll
    for (int ct = 0; ct < 2; ++ct) {
      int c = n0 + 16 * ct + lr;
      float tt = t3[c];
      #pragma unroll
      for (int i = 0; i < 4; ++i) {
        int r = m0 + 16 * rt + rbase + i;
        D[(size_t)r * NC + c] = acc[rt][ct][i] + tt;
      }
    }
  }
}

// ---------- epilogue: softmax over C, S, per-block(4-row) loss partials ----------
// 4 waves/block, 1 row per wave; lane owns cols lane+64j (scalar, fully coalesced).
__global__ __launch_bounds__(256) void k_epi(const int* __restrict__ T,
                                             const int* __restrict__ colnz,
                                             const int* __restrict__ pos,
                                             const float* __restrict__ Din,
                                             float* __restrict__ Sout,
                                             float* __restrict__ blklog,
                                             int* __restrict__ blkcnt,
                                             int Csel, int ident) {
  __shared__ float sl4[4];
  __shared__ int sc4[4];
  int lane = threadIdx.x & 63, w = threadIdx.x >> 6;
  int r = blockIdx.x * 4 + w;
  const float* drow = Din + (size_t)r * NC;
  const int* Trow = T + (size_t)r * NC;
  float d[8]; int tf[8];
  #pragma unroll
  for (int j = 0; j < 8; ++j) {
    d[j] = drow[lane + 64 * j];
    tf[j] = Trow[lane + 64 * j];
  }
  float dmin = d[0];
  #pragma unroll
  for (int j = 1; j < 8; ++j) dmin = fminf(dmin, d[j]);
  #pragma unroll
  for (int o = 1; o < 64; o <<= 1) dmin = fminf(dmin, __shfl_xor(dmin, o, 64));
  float Z = 0.f, Ps = 0.f;
  #pragma unroll
  for (int j = 0; j < 8; ++j) {
    float p = __expf(TAUc * (dmin - d[j]));
    Z += p;
    if (tf[j]) Ps += p;
  }
  #pragma unroll
  for (int o = 1; o < 64; o <<= 1) { Z += __shfl_xor(Z, o, 64); Ps += __shfl_xor(Ps, o, 64); }
  float sv[8];
  #pragma unroll
  for (int j = 0; j < 8; ++j) sv[j] = tf[j] ? 1.0f : __expf(-ALPHAc * d[j]);
  float* srow = Sout + (size_t)r * Csel;
  if (ident) {
    #pragma unroll
    for (int j = 0; j < 8; ++j) srow[lane + 64 * j] = sv[j];
  } else {
    #pragma unroll
    for (int j = 0; j < 8; ++j) {
      int c = lane + 64 * j;
      if (colnz[c]) srow[pos[c]] = sv[j];
    }
  }
  if (lane == 0) {
    float Psum = Ps / Z;
    sl4[w] = (Psum > 0.f) ? logf(Psum) : 0.f;
    sc4[w] = (Psum > 0.f) ? 1 : 0;
  }
  __syncthreads();
  if (threadIdx.x == 0) {
    blklog[blockIdx.x] = sl4[0] + sl4[1] + sl4[2] + sl4[3];
    blkcnt[blockIdx.x] = sc4[0] + sc4[1] + sc4[2] + sc4[3];
  }
}

// ---------- finalize loss (reads NB/4 partials) ----------------------------------
__global__ __launch_bounds__(256) void k_fin(const float* __restrict__ blklog,
                                             const int* __restrict__ blkcnt,
                                             float* __restrict__ out) {
  __shared__ float sl[256];
  __shared__ int sc[256];
  int t = threadIdx.x;
  float s = 0.f; int c = 0;
  for (int r = t; r < NB / 4; r += 256) { s += blklog[r]; c += blkcnt[r]; }
  sl[t] = s; sc[t] = c;
  __syncthreads();
  for (int o = 128; o > 0; o >>= 1) {
    if (t < o) { sl[t] += sl[t + o]; sc[t] += sc[t + o]; }
    __syncthreads();
  }
  if (t == 0) out[0] = -sl[0] / fmaxf((float)sc[0], 1.0f);
}

extern "C" void kernel_launch(void* const* d_in, const int* in_sizes, int n_in,
                              void* d_out, int out_size, void* d_ws, size_t ws_size,
                              hipStream_t stream) {
  const float* X     = (const float*)d_in[0];
  const int*   T     = (const int*)d_in[1];
  const float* means = (const float*)d_in[2];
  const float* logv  = (const float*)d_in[3];
  float* out = (float*)d_out;
  char* ws = (char*)d_ws;

  ushort* Ah    = (ushort*)(ws);                       // 2 MB
  ushort* Al    = (ushort*)(ws + 2097152);             // 2 MB
  ushort* Bh    = (ushort*)(ws + 4194304);             // 256 KB
  ushort* Bl    = (ushort*)(ws + 4456448);             // 256 KB
  float*  t3    = (float*) (ws + 4718592);             // 2 KB
  float*  blklog= (float*) (ws + 4720640);             // 4 KB
  int*    blkcnt= (int*)   (ws + 4724736);             // 4 KB
  int*    colnz = (int*)   (ws + 4728832);             // 2 KB
  int*    pos   = (int*)   (ws + 4730880);             // 2 KB
  float*  Dfb   = (float*) (ws + 4732928);             // 8 MB fallback (Csel<512 only)

  int Csel = (out_size - 1) / NB;
  int ident = (Csel == NC);
  // Csel==NC forces the all-ones mask (pos = identity) -> skip mask machinery.
  float* Din = ident ? (out + 1) : Dfb;

  k_prep<<<NB + NC, NF, 0, stream>>>(X, means, logv, Ah, Al, Bh, Bl, t3);
  if (!ident) {
    k_zero<<<1, NC, 0, stream>>>(colnz);
    k_mask<<<NB / 16, 256, 0, stream>>>(T, colnz);
    k_scan<<<1, NC, 0, stream>>>(colnz, pos);
  }
  k_gemm<<<dim3(NB / 64, NC / 64), 256, 0, stream>>>(Ah, Al, Bh, Bl, t3, Din);
  k_epi<<<NB / 4, 256, 0, stream>>>(T, colnz, pos, Din, out + 1, blklog, blkcnt, Csel, ident);
  k_fin<<<1, 256, 0, stream>>>(blklog, blkcnt, out);
}

// Round 4
// 32.826 us; speedup vs baseline: 2.2340x; 1.3712x over previous
//
#include <hip/hip_runtime.h>
#include <hip/hip_bf16.h>
#include <math.h>

#define NB 4096
#define NC 512
#define NF 128
#define NK 256           // GEMM K = 2*F  (k<128: xn^2 . iv ; k>=128: xn . -2*mu*iv)
#define TAUc 32.0f
#define ALPHAc 0.9f

typedef __attribute__((ext_vector_type(8))) short bf16x8;
typedef __attribute__((ext_vector_type(4))) float f32x4;

__device__ inline ushort f2bf(float x) {
  __hip_bfloat16 h = __float2bfloat16(x);
  return *reinterpret_cast<ushort*>(&h);
}
__device__ inline float bf2f(ushort u) {
  __hip_bfloat16 h = *reinterpret_cast<__hip_bfloat16*>(&u);
  return __bfloat162float(h);
}

// ---------- prepB: mu_n, iv=exp(-clip(lv)); B = [iv, -2*mu_n*iv] hi/lo; t3 -------
__global__ __launch_bounds__(128) void k_prepB(const float* __restrict__ means,
                                               const float* __restrict__ logv,
                                               ushort* __restrict__ Bh,
                                               ushort* __restrict__ Bl,
                                               float* __restrict__ t3) {
  __shared__ float p2[2];
  __shared__ float q2[2];
  int c = blockIdx.x, f = threadIdx.x;
  float mu = means[(size_t)c * NF + f];
  float lv = fminf(fmaxf(logv[(size_t)c * NF + f], 0.f), 6.f);
  float iv = __expf(-lv);
  float s = mu * mu;
  #pragma unroll
  for (int o = 1; o < 64; o <<= 1) s += __shfl_xor(s, o, 64);
  if ((f & 63) == 0) p2[f >> 6] = s;
  __syncthreads();
  float mun = mu / fmaxf(sqrtf(p2[0] + p2[1]), 1e-12f);
  float b1 = iv;
  float b2 = -2.f * mun * iv;
  ushort h1 = f2bf(b1);
  Bh[(size_t)c * NK + f] = h1;
  Bl[(size_t)c * NK + f] = f2bf(b1 - bf2f(h1));
  ushort h2 = f2bf(b2);
  Bh[(size_t)c * NK + NF + f] = h2;
  Bl[(size_t)c * NK + NF + f] = f2bf(b2 - bf2f(h2));
  float t = mun * mun * iv;
  #pragma unroll
  for (int o = 1; o < 64; o <<= 1) t += __shfl_xor(t, o, 64);
  if ((f & 63) == 0) q2[f >> 6] = t;
  __syncthreads();
  if (f == 0) t3[c] = q2[0] + q2[1];
}

// ---------- fallback-only mask machinery (not launched when Csel==NC) ------------
__global__ __launch_bounds__(512) void k_zero(int* __restrict__ colnz) {
  colnz[threadIdx.x] = 0;
}

__global__ __launch_bounds__(256) void k_mask(const int* __restrict__ T,
                                              int* __restrict__ colnz) {
  int r0 = blockIdx.x * 16;
  int a0 = 0, a1 = 0;
  for (int r = 0; r < 16; ++r) {
    const int* row = T + (size_t)(r0 + r) * NC;
    a0 |= row[threadIdx.x];
    a1 |= row[threadIdx.x + 256];
  }
  if (a0) atomicOr(colnz + threadIdx.x, 1);
  if (a1) atomicOr(colnz + threadIdx.x + 256, 1);
}

__global__ __launch_bounds__(512) void k_scan(const int* __restrict__ colnz,
                                              int* __restrict__ pos) {
  __shared__ int s[NC];
  int t = threadIdx.x;
  int f = colnz[t] ? 1 : 0;
  s[t] = f;
  __syncthreads();
  for (int o = 1; o < NC; o <<= 1) {
    int add = (t >= o) ? s[t - o] : 0;
    __syncthreads();
    s[t] += add;
    __syncthreads();
  }
  pos[t] = s[t] - f;
}

// ---------- fused: X-normalize + split-bf16 GEMM + softmax + S + loss partials ---
// grid = NB/16 = 256 blocks, 512 threads = 8 waves. Block tile: 16 rows x 512 cols.
// Wave w owns cols [64w, 64w+64). A (16 rows, K=256, hi+lo) lives in registers,
// built in-place from X. B read from global (L2-resident, 1 MB). D never leaves
// the block: acc -> LDS -> softmax/S/loss in the same kernel.
__global__ __launch_bounds__(512) void k_fused(const float* __restrict__ X,
                                               const int* __restrict__ T,
                                               const ushort* __restrict__ Bh,
                                               const ushort* __restrict__ Bl,
                                               const float* __restrict__ t3,
                                               const int* __restrict__ colnz,
                                               const int* __restrict__ pos,
                                               float* __restrict__ Sout,
                                               float* __restrict__ blklog,
                                               int* __restrict__ blkcnt,
                                               int Csel, int ident) {
  __shared__ float Dls[16][520];   // 520-word stride: rows hit distinct bank groups
  __shared__ float sl16[16];
  __shared__ int sc16[16];
  int tid = threadIdx.x;
  int lane = tid & 63, w = tid >> 6;
  int lr = lane & 15, kq = lane >> 4;
  int r0 = blockIdx.x * 16;
  int n0 = w * 64;

  // ---- build A fragments in registers ----
  // lane covers row (r0+lr), k-slices k = 32c + 8kq + j  (j=0..7, c=0..7)
  // c<4 -> xn^2 at f=32c+8kq+j ; c>=4 -> xn at same f (f = k mod 128)
  float xv[4][8];
  float rsum = 0.f;
  const float* xrow = X + (size_t)(r0 + lr) * NF + 8 * kq;
  #pragma unroll
  for (int c = 0; c < 4; ++c) {
    float4 u0 = *(const float4*)(xrow + 32 * c);
    float4 u1 = *(const float4*)(xrow + 32 * c + 4);
    xv[c][0] = u0.x; xv[c][1] = u0.y; xv[c][2] = u0.z; xv[c][3] = u0.w;
    xv[c][4] = u1.x; xv[c][5] = u1.y; xv[c][6] = u1.z; xv[c][7] = u1.w;
    #pragma unroll
    for (int j = 0; j < 8; ++j) rsum = fmaf(xv[c][j], xv[c][j], rsum);
  }
  // lanes lr, lr+16, lr+32, lr+48 share a row: xor-16 + xor-32 completes the sum
  rsum += __shfl_xor(rsum, 16, 64);
  rsum += __shfl_xor(rsum, 32, 64);
  float rn = 1.0f / fmaxf(sqrtf(rsum), 1e-12f);

  bf16x8 Afh[8], Afl[8];
  #pragma unroll
  for (int c = 0; c < 4; ++c) {
    #pragma unroll
    for (int j = 0; j < 8; ++j) {
      float xn = xv[c][j] * rn;
      float a2 = xn * xn;
      ushort h2 = f2bf(a2);
      Afh[c][j] = (short)h2;
      Afl[c][j] = (short)f2bf(a2 - bf2f(h2));
      ushort h1 = f2bf(xn);
      Afh[c + 4][j] = (short)h1;
      Afl[c + 4][j] = (short)f2bf(xn - bf2f(h1));
    }
  }

  // ---- MFMA main loop: 3-product split-bf16, acc over col tiles t=0..3 ----
  f32x4 acc[4] = {};
  const ushort* bhp = Bh + (size_t)(n0 + lr) * NK + 8 * kq;
  const ushort* blp = Bl + (size_t)(n0 + lr) * NK + 8 * kq;
  #pragma unroll
  for (int k8 = 0; k8 < 8; ++k8) {
    #pragma unroll
    for (int t = 0; t < 4; ++t) {
      bf16x8 bh = *(const bf16x8*)(bhp + (size_t)(16 * t) * NK + 32 * k8);
      bf16x8 bl = *(const bf16x8*)(blp + (size_t)(16 * t) * NK + 32 * k8);
      acc[t] = __builtin_amdgcn_mfma_f32_16x16x32_bf16(Afh[k8], bh, acc[t], 0, 0, 0);
      acc[t] = __builtin_amdgcn_mfma_f32_16x16x32_bf16(Afl[k8], bh, acc[t], 0, 0, 0);
      acc[t] = __builtin_amdgcn_mfma_f32_16x16x32_bf16(Afh[k8], bl, acc[t], 0, 0, 0);
    }
  }

  // ---- D tile -> LDS (add t3), C/D layout: col=lane&15, row=4*kq+i ----
  #pragma unroll
  for (int t = 0; t < 4; ++t) {
    int c = n0 + 16 * t + lr;
    float tt = t3[c];
    #pragma unroll
    for (int i = 0; i < 4; ++i) Dls[4 * kq + i][c] = acc[t][i] + tt;
  }
  __syncthreads();

  // ---- per-row softmax + S + loss terms; wave w handles rows 2w, 2w+1 ----
  #pragma unroll
  for (int rr = 0; rr < 2; ++rr) {
    int r = 2 * w + rr;
    const int* Trow = T + (size_t)(r0 + r) * NC;
    float d[8]; int tf[8];
    #pragma unroll
    for (int j = 0; j < 8; ++j) {
      d[j] = Dls[r][lane + 64 * j];
      tf[j] = Trow[lane + 64 * j];
    }
    float dmin = d[0];
    #pragma unroll
    for (int j = 1; j < 8; ++j) dmin = fminf(dmin, d[j]);
    #pragma unroll
    for (int o = 1; o < 64; o <<= 1) dmin = fminf(dmin, __shfl_xor(dmin, o, 64));
    float Z = 0.f, Ps = 0.f;
    #pragma unroll
    for (int j = 0; j < 8; ++j) {
      float p = __expf(TAUc * (dmin - d[j]));
      Z += p;
      if (tf[j]) Ps += p;
    }
    #pragma unroll
    for (int o = 1; o < 64; o <<= 1) { Z += __shfl_xor(Z, o, 64); Ps += __shfl_xor(Ps, o, 64); }
    float* srow = Sout + (size_t)(r0 + r) * Csel;
    if (ident) {
      #pragma unroll
      for (int j = 0; j < 8; ++j)
        srow[lane + 64 * j] = tf[j] ? 1.0f : __expf(-ALPHAc * d[j]);
    } else {
      #pragma unroll
      for (int j = 0; j < 8; ++j) {
        int c = lane + 64 * j;
        if (colnz[c]) srow[pos[c]] = tf[j] ? 1.0f : __expf(-ALPHAc * d[j]);
      }
    }
    if (lane == 0) {
      float Psum = Ps / Z;
      sl16[r] = (Psum > 0.f) ? logf(Psum) : 0.f;
      sc16[r] = (Psum > 0.f) ? 1 : 0;
    }
  }
  __syncthreads();
  if (tid == 0) {
    float s = 0.f; int c = 0;
    #pragma unroll
    for (int r = 0; r < 16; ++r) { s += sl16[r]; c += sc16[r]; }
    blklog[blockIdx.x] = s;
    blkcnt[blockIdx.x] = c;
  }
}

// ---------- finalize loss (reads NB/16 = 256 partials) ---------------------------
__global__ __launch_bounds__(256) void k_fin(const float* __restrict__ blklog,
                                             const int* __restrict__ blkcnt,
                                             float* __restrict__ out) {
  __shared__ float sl[256];
  __shared__ int sc[256];
  int t = threadIdx.x;
  float s = blklog[t];
  int c = blkcnt[t];
  sl[t] = s; sc[t] = c;
  __syncthreads();
  for (int o = 128; o > 0; o >>= 1) {
    if (t < o) { sl[t] += sl[t + o]; sc[t] += sc[t + o]; }
    __syncthreads();
  }
  if (t == 0) out[0] = -sl[0] / fmaxf((float)sc[0], 1.0f);
}

extern "C" void kernel_launch(void* const* d_in, const int* in_sizes, int n_in,
                              void* d_out, int out_size, void* d_ws, size_t ws_size,
                              hipStream_t stream) {
  const float* X     = (const float*)d_in[0];
  const int*   T     = (const int*)d_in[1];
  const float* means = (const float*)d_in[2];
  const float* logv  = (const float*)d_in[3];
  float* out = (float*)d_out;
  char* ws = (char*)d_ws;

  ushort* Bh    = (ushort*)(ws);                  // 256 KB
  ushort* Bl    = (ushort*)(ws + 262144);         // 256 KB
  float*  t3    = (float*) (ws + 524288);         // 2 KB
  float*  blklog= (float*) (ws + 526336);         // 1 KB
  int*    blkcnt= (int*)   (ws + 527360);         // 1 KB
  int*    colnz = (int*)   (ws + 528384);         // 2 KB
  int*    pos   = (int*)   (ws + 530432);         // 2 KB

  int Csel = (out_size - 1) / NB;
  int ident = (Csel == NC);   // Csel==NC forces all-ones mask (pos = identity)

  k_prepB<<<NC, NF, 0, stream>>>(means, logv, Bh, Bl, t3);
  if (!ident) {
    k_zero<<<1, NC, 0, stream>>>(colnz);
    k_mask<<<NB / 16, 256, 0, stream>>>(T, colnz);
    k_scan<<<1, NC, 0, stream>>>(colnz, pos);
  }
  k_fused<<<NB / 16, 512, 0, stream>>>(X, T, Bh, Bl, t3, colnz, pos,
                                       out + 1, blklog, blkcnt, Csel, ident);
  k_fin<<<1, 256, 0, stream>>>(blklog, blkcnt, out);
}